// Round 10
// baseline (722.144 us; speedup 1.0000x reference)
//
#include <hip/hip_runtime.h>
#include <hip/hip_bf16.h>
#include <float.h>

// ---------------------------------------------------------------------------
// NonOverlappingFlatVQVAE forward, MI355X (gfx950).
// Round 8/9/10: split-once bf16 h/l mirrors + 2-phase double-buffered
// global_load_lds pipeline for ALL matmuls (GEMMs and VQ scan).
//   encoder GEMMs : bf16x2, 4 passes (hh+hl+lh+ll)  [R7-verified numerics]
//   decoder GEMMs : bf16x2, 3 passes                [R7-verified numerics]
//   VQ stage 1    : bf16-hi scan, top-2 per 16 slots -> 32 cand/token
//   VQ stage 2    : exact f64 rescore -> true argmin + diff [R6-verified]
// ws budget: 63,209,472 B  (ws_size >= 68,976,640 proven by R6 profile:
// vq_mfma2 [the use_mfma branch] appeared in the dispatch list).
// Harness reads d_out as f32 -> idx written as float values.
// ---------------------------------------------------------------------------

#define TOK   8192
#define CBK   8192
#define CBD   512

typedef short  short8v __attribute__((ext_vector_type(8)));
typedef float  f32x4   __attribute__((ext_vector_type(4)));
typedef unsigned short ush;

__device__ __forceinline__ unsigned short f2bf(float x) {
    union { __hip_bfloat16 b; unsigned short u; } c;
    c.b = __float2bfloat16(x);
    return c.u;
}
__device__ __forceinline__ float bf2f(unsigned short h) {
    return __uint_as_float((unsigned)h << 16);
}

// direct global->LDS 16B copy; LDS dest is wave-uniform base + lane*16 (HW).
__device__ __forceinline__ void gload16(const void* g, void* l) {
    __builtin_amdgcn_global_load_lds(
        (const __attribute__((address_space(1))) unsigned int*)g,
        (__attribute__((address_space(3))) unsigned int*)l, 16, 0, 0);
}

// ======================= pipelined bf16x2 MFMA GEMM ========================
// C[M,N] = A[M,K] x Bw[N,K]^T + bias. Tile 128x64, K-step 64, 4 waves (2x2).
// LDS 96KB: double-buffered Ah/Al (16KB ea) + Bh/Bl (8KB ea).
// Staging: global_load_lds w16, source pre-swizzled chunk c = p ^ (r&7)
// (linear LDS dest), read with the same XOR -> conflict-free (R6: 0 conflicts).
// AMODE: 0 dense, 2 row-gather via float idx. STMODE: 0 ->(Ch,Cl) bf16 pair,
// 1 -> Cf f32 + Ch bf16, 2 -> f32 scatter to dec[B,3,256,256] (bias[n>>8]).
template<int NPASS, int AMODE, int STMODE, bool RELU>
__global__ __launch_bounds__(256)
void gemm_bf2(const ush* __restrict__ Ah, const ush* __restrict__ Al,
              const ush* __restrict__ Bh, const ush* __restrict__ Bl,
              const float* __restrict__ bias,
              float* __restrict__ Cf, ush* __restrict__ Ch, ush* __restrict__ Cl,
              const float* __restrict__ rowidx, int N, int K, int NT)
{
    __shared__ __align__(16) ush AzH[2][128 * 64];
    __shared__ __align__(16) ush AzL[2][128 * 64];
    __shared__ __align__(16) ush BcH[2][64 * 64];
    __shared__ __align__(16) ush BcL[2][64 * 64];

    const int tid = threadIdx.x, lane = tid & 63, wid = tid >> 6;
    const int wr = wid >> 1, wc = wid & 1;
    const int m0 = blockIdx.x * 128, n0 = blockIdx.y * 64;
    const int l15 = lane & 15, l4 = lane >> 4;

    // per-lane staging source offsets (elements); per-wave LDS chunk bases
    size_t aoff[4];
    int    aldst[4];
    #pragma unroll
    for (int i = 0; i < 4; ++i) {
        const int ci = (wid * 4 + i) * 64 + lane;
        const int r = ci >> 3, p = ci & 7;
        size_t rowbase;
        if constexpr (AMODE == 2) rowbase = (size_t)((int)rowidx[m0 + r]) * K;
        else                      rowbase = (size_t)(m0 + r) * K;
        aoff[i]  = rowbase + ((p ^ (r & 7)) << 3);
        aldst[i] = (wid * 4 + i) * 512;
    }
    size_t boff[2];
    int    bldst[2];
    #pragma unroll
    for (int i = 0; i < 2; ++i) {
        const int ci = (wid * 2 + i) * 64 + lane;
        const int r = ci >> 3, p = ci & 7;
        boff[i]  = (size_t)(n0 + r) * K + ((p ^ (r & 7)) << 3);
        bldst[i] = (wid * 2 + i) * 512;
    }

    auto STAGE = [&](int t, int b) {
        const int k0 = t << 6;
        #pragma unroll
        for (int i = 0; i < 4; ++i) {
            gload16(Ah + aoff[i] + k0, &AzH[b][aldst[i]]);
            gload16(Al + aoff[i] + k0, &AzL[b][aldst[i]]);
        }
        #pragma unroll
        for (int i = 0; i < 2; ++i) {
            gload16(Bh + boff[i] + k0, &BcH[b][bldst[i]]);
            gload16(Bl + boff[i] + k0, &BcL[b][bldst[i]]);
        }
    };

    f32x4 acc[4][2];
    #pragma unroll
    for (int mi = 0; mi < 4; ++mi)
        #pragma unroll
        for (int nj = 0; nj < 2; ++nj)
            acc[mi][nj] = (f32x4){0.f, 0.f, 0.f, 0.f};

    STAGE(0, 0);
    __syncthreads();
    for (int t = 0; t < NT; ++t) {
        const int b = t & 1;
        if (t + 1 < NT) STAGE(t + 1, b ^ 1);
        #pragma unroll
        for (int ks = 0; ks < 2; ++ks) {
            short8v aFh[4], aFl[4];
            #pragma unroll
            for (int mi = 0; mi < 4; ++mi) {
                const int r = wr * 64 + mi * 16 + l15;
                const int off = r * 64 + (((ks * 4 + l4) ^ (r & 7)) << 3);
                aFh[mi] = *(const short8v*)(&AzH[b][off]);
                aFl[mi] = *(const short8v*)(&AzL[b][off]);
            }
            #pragma unroll
            for (int nj = 0; nj < 2; ++nj) {
                const int rn = wc * 32 + nj * 16 + l15;
                const int off = rn * 64 + (((ks * 4 + l4) ^ (rn & 7)) << 3);
                const short8v bh = *(const short8v*)(&BcH[b][off]);
                const short8v bl = *(const short8v*)(&BcL[b][off]);
                #pragma unroll
                for (int mi = 0; mi < 4; ++mi) {
                    acc[mi][nj] = __builtin_amdgcn_mfma_f32_16x16x32_bf16(aFh[mi], bh, acc[mi][nj], 0, 0, 0);
                    acc[mi][nj] = __builtin_amdgcn_mfma_f32_16x16x32_bf16(aFh[mi], bl, acc[mi][nj], 0, 0, 0);
                    acc[mi][nj] = __builtin_amdgcn_mfma_f32_16x16x32_bf16(aFl[mi], bh, acc[mi][nj], 0, 0, 0);
                    if constexpr (NPASS == 4)
                        acc[mi][nj] = __builtin_amdgcn_mfma_f32_16x16x32_bf16(aFl[mi], bl, acc[mi][nj], 0, 0, 0);
                }
            }
        }
        __syncthreads();
    }

    // epilogue: C/D layout col=lane&15 (n), row=(lane>>4)*4+i (m) [R6-verified]
    #pragma unroll
    for (int nj = 0; nj < 2; ++nj) {
        const int n = n0 + wc * 32 + nj * 16 + l15;
        const float bv = (STMODE == 2) ? bias[n >> 8] : bias[n];
        #pragma unroll
        for (int mi = 0; mi < 4; ++mi) {
            #pragma unroll
            for (int i = 0; i < 4; ++i) {
                const int m = m0 + wr * 64 + mi * 16 + l4 * 4 + i;
                float v = acc[mi][nj][i] + bv;
                if constexpr (RELU) v = fmaxf(v, 0.f);
                if constexpr (STMODE == 0) {
                    const unsigned short h = f2bf(v);
                    Ch[(size_t)m * N + n] = h;
                    Cl[(size_t)m * N + n] = f2bf(v - bf2f(h));
                } else if constexpr (STMODE == 1) {
                    Cf[(size_t)m * N + n] = v;
                    Ch[(size_t)m * N + n] = f2bf(v);
                } else {
                    const int o = n >> 8, p = (n >> 4) & 15, q = n & 15;
                    const int b2 = m >> 8, ii = (m >> 4) & 15, jj = m & 15;
                    Cf[((size_t)(b2 * 3 + o) * 256 + ii * 16 + p) * 256 + jj * 16 + q] = v;
                }
            }
        }
    }
}

// ================== pipelined VQ stage 1 (bf16-hi scan) ====================
// Grid 64 x 8; block 4 waves (2x2), tile 128 tok x 128 codes, K-step 64.
// LDS 64KB double-buffered. Flattened (chk,k) loop of 64 iters, prefetch t+1.
__global__ __launch_bounds__(256)
void vq_scan(const ush* __restrict__ zh, const ush* __restrict__ cbh,
             const float* __restrict__ cnorm, int* __restrict__ cand)
{
    __shared__ __align__(16) ush Az[2][128 * 64];
    __shared__ __align__(16) ush Bc[2][128 * 64];

    const int tid = threadIdx.x, lane = tid & 63, wid = tid >> 6;
    const int wr = wid >> 1, wc = wid & 1;
    const int m0 = blockIdx.x * 128;
    const int cy = blockIdx.y;
    const int l15 = lane & 15, l4 = lane >> 4;

    size_t soff[4];
    int    ldst[4];
    #pragma unroll
    for (int i = 0; i < 4; ++i) {
        const int ci = (wid * 4 + i) * 64 + lane;
        const int r = ci >> 3, p = ci & 7;
        soff[i] = (size_t)r * CBD + ((p ^ (r & 7)) << 3);
        ldst[i] = (wid * 4 + i) * 512;
    }

    auto STAGE = [&](int t, int b) {
        const int chk = t >> 3, k0 = (t & 7) << 6;
        const size_t ab = (size_t)m0 * CBD + k0;
        const size_t bb = (size_t)(cy * 1024 + chk * 128) * CBD + k0;
        #pragma unroll
        for (int i = 0; i < 4; ++i) {
            gload16(zh  + ab + soff[i], &Az[b][ldst[i]]);
            gload16(cbh + bb + soff[i], &Bc[b][ldst[i]]);
        }
    };

    float r1[16], r2[16];
    int   i1[16], i2[16];
    #pragma unroll
    for (int r = 0; r < 16; ++r) { r1[r] = FLT_MAX; r2[r] = FLT_MAX; i1[r] = 0; i2[r] = 0; }

    f32x4 acc[4][4];
    STAGE(0, 0);
    __syncthreads();
    for (int t = 0; t < 64; ++t) {
        const int b = t & 1;
        if (t < 63) STAGE(t + 1, b ^ 1);
        if ((t & 7) == 0) {
            #pragma unroll
            for (int mi = 0; mi < 4; ++mi)
                #pragma unroll
                for (int nj = 0; nj < 4; ++nj)
                    acc[mi][nj] = (f32x4){0.f, 0.f, 0.f, 0.f};
        }
        #pragma unroll
        for (int ks = 0; ks < 2; ++ks) {
            short8v aF[4];
            #pragma unroll
            for (int mi = 0; mi < 4; ++mi) {
                const int r = wr * 64 + mi * 16 + l15;
                aF[mi] = *(const short8v*)(&Az[b][r * 64 + (((ks * 4 + l4) ^ (r & 7)) << 3)]);
            }
            #pragma unroll
            for (int nj = 0; nj < 4; ++nj) {
                const int rn = wc * 64 + nj * 16 + l15;
                const short8v bF = *(const short8v*)(&Bc[b][rn * 64 + (((ks * 4 + l4) ^ (rn & 7)) << 3)]);
                #pragma unroll
                for (int mi = 0; mi < 4; ++mi)
                    acc[mi][nj] = __builtin_amdgcn_mfma_f32_16x16x32_bf16(aF[mi], bF, acc[mi][nj], 0, 0, 0);
            }
        }
        if ((t & 7) == 7) {
            const int c0 = cy * 1024 + (t >> 3) * 128;
            #pragma unroll
            for (int nj = 0; nj < 4; ++nj) {
                const int code = c0 + wc * 64 + nj * 16 + l15;
                const float cn = cnorm[code];
                #pragma unroll
                for (int mi = 0; mi < 4; ++mi) {
                    #pragma unroll
                    for (int i = 0; i < 4; ++i) {
                        const float d = cn - 2.0f * acc[mi][nj][i];
                        const int rr = mi * 4 + i;
                        if (d < r1[rr]) { r2[rr] = r1[rr]; i2[rr] = i1[rr]; r1[rr] = d; i1[rr] = code; }
                        else if (d < r2[rr]) { r2[rr] = d; i2[rr] = code; }
                    }
                }
            }
        }
        __syncthreads();
    }

    // merge top-2 across the 16 l15 lanes sharing each token row
    #pragma unroll
    for (int r = 0; r < 16; ++r) {
        float a1 = r1[r], a2 = r2[r];
        int   x1 = i1[r], x2 = i2[r];
        #pragma unroll
        for (int off = 1; off < 16; off <<= 1) {
            const float b1 = __shfl_xor(a1, off), b2 = __shfl_xor(a2, off);
            const int   y1 = __shfl_xor(x1, off), y2 = __shfl_xor(x2, off);
            if (b1 < a1) {
                const float n2 = (a1 < b2) ? a1 : b2;
                const int   m2 = (a1 < b2) ? x1 : y2;
                a2 = n2; x2 = m2; a1 = b1; x1 = y1;
            } else {
                if (b1 < a2) { a2 = b1; x2 = y1; }
            }
        }
        r1[r] = a1; i1[r] = x1; r2[r] = a2; i2[r] = x2;
    }
    if (l15 == 0) {
        const int slot = cy * 2 + wc;
        #pragma unroll
        for (int mi = 0; mi < 4; ++mi)
            #pragma unroll
            for (int i = 0; i < 4; ++i) {
                const int tok = m0 + wr * 64 + mi * 16 + l4 * 4 + i;
                cand[(slot * 2 + 0) * TOK + tok] = i1[mi * 4 + i];
                cand[(slot * 2 + 1) * TOK + tok] = i2[mi * 4 + i];
            }
    }
}

// ============ stage 2: exact f64 rescore of candidates + diff ==============
__global__ __launch_bounds__(256)
void exact_select(const float* __restrict__ z, const float* __restrict__ cb,
                  const int* __restrict__ cand, int ncand,
                  float* __restrict__ idx_out, float* __restrict__ diffp)
{
    const int t    = blockIdx.x * 4 + (threadIdx.x >> 6);
    const int lane = threadIdx.x & 63;

    const float4 za = *(const float4*)(z + (size_t)t * CBD + lane * 8);
    const float4 zb = *(const float4*)(z + (size_t)t * CBD + lane * 8 + 4);
    const double zd[8] = {za.x, za.y, za.z, za.w, zb.x, zb.y, zb.z, zb.w};

    double bestd = DBL_MAX;
    int    besti = 0x7fffffff;
    for (int c = 0; c < ncand; ++c) {
        const int code = cand[c * TOK + t];
        const float4 ca  = *(const float4*)(cb + (size_t)code * CBD + lane * 8);
        const float4 cbv = *(const float4*)(cb + (size_t)code * CBD + lane * 8 + 4);
        const double cd[8] = {ca.x, ca.y, ca.z, ca.w, cbv.x, cbv.y, cbv.z, cbv.w};
        double s = 0.0;
        #pragma unroll
        for (int j = 0; j < 8; ++j) { const double d = cd[j] - zd[j]; s = fma(d, d, s); }
        #pragma unroll
        for (int off = 32; off >= 1; off >>= 1) s += __shfl_down(s, off);
        s = __shfl(s, 0);
        if (s < bestd || (s == bestd && code < besti)) { bestd = s; besti = code; }
    }
    if (lane == 0) {
        idx_out[t] = (float)besti;
        atomicAdd(diffp, (float)(bestd * (1.0 / ((double)TOK * CBD))));
    }
}

// ============================ prep kernels =================================
__global__ __launch_bounds__(256)
void cb_norm(const float* __restrict__ cb, float* __restrict__ cnorm)
{
    const int row  = blockIdx.x * 4 + (threadIdx.x >> 6);
    const int lane = threadIdx.x & 63;
    const float4* p = (const float4*)(cb + (size_t)row * CBD + lane * 8);
    const float4 a = p[0], b = p[1];
    double s = (double)a.x*a.x + (double)a.y*a.y + (double)a.z*a.z + (double)a.w*a.w
             + (double)b.x*b.x + (double)b.y*b.y + (double)b.z*b.z + (double)b.w*b.w;
    #pragma unroll
    for (int off = 32; off >= 1; off >>= 1) s += __shfl_down(s, off);
    if (lane == 0) cnorm[row] = (float)s;
}

// f32 -> (h,l) split, 8 elems/thread (n % 2048 == 0)
__global__ __launch_bounds__(256)
void split_hl(const float* __restrict__ src, ush* __restrict__ h, ush* __restrict__ l)
{
    const size_t i8 = (size_t)blockIdx.x * 256 + threadIdx.x;
    const float4 a = *(const float4*)(src + i8 * 8);
    const float4 b = *(const float4*)(src + i8 * 8 + 4);
    const float xs[8] = {a.x, a.y, a.z, a.w, b.x, b.y, b.z, b.w};
    union { unsigned short u[8]; short8v v; } H, L;
    #pragma unroll
    for (int j = 0; j < 8; ++j) {
        const unsigned short hh = f2bf(xs[j]);
        H.u[j] = hh;
        L.u[j] = f2bf(xs[j] - bf2f(hh));
    }
    *(short8v*)(h + i8 * 8) = H.v;
    *(short8v*)(l + i8 * 8) = L.v;
}

// patchify gather + split: x[32,3,256,256] -> xph/xpl [8192][768]
__global__ __launch_bounds__(256)
void split_x(const float* __restrict__ x, ush* __restrict__ xh, ush* __restrict__ xl)
{
    const int i8 = blockIdx.x * 256 + threadIdx.x;   // < 786432
    const int m = i8 / 96, kc = (i8 % 96) * 8;
    const int b = m >> 8, ii = (m >> 4) & 15, jj = m & 15;
    const int c = kc >> 8, p = (kc >> 4) & 15, q = kc & 15;
    const float* src = x + ((size_t)(b * 3 + c) * 256 + ii * 16 + p) * 256 + jj * 16 + q;
    const float4 a = *(const float4*)src;
    const float4 d = *(const float4*)(src + 4);
    const float xs[8] = {a.x, a.y, a.z, a.w, d.x, d.y, d.z, d.w};
    union { unsigned short u[8]; short8v v; } H, L;
    #pragma unroll
    for (int j = 0; j < 8; ++j) {
        const unsigned short hh = f2bf(xs[j]);
        H.u[j] = hh;
        L.u[j] = f2bf(xs[j] - bf2f(hh));
    }
    *(short8v*)(xh + (size_t)i8 * 8) = H.v;
    *(short8v*)(xl + (size_t)i8 * 8) = L.v;
}

// up_w [256,768] -> upT h/l [768][256]
__global__ __launch_bounds__(256)
void transpose_upw_split(const float* __restrict__ up_w, ush* __restrict__ th, ush* __restrict__ tl)
{
    const int id = blockIdx.x * 256 + threadIdx.x;   // < 196608
    const int n = id >> 8, c = id & 255;
    const float v = up_w[c * 768 + n];
    const unsigned short h = f2bf(v);
    th[id] = h;
    tl[id] = f2bf(v - bf2f(h));
}

// ---------------------------------------------------------------------------
extern "C" void kernel_launch(void* const* d_in, const int* in_sizes, int n_in,
                              void* d_out, int out_size, void* d_ws, size_t ws_size,
                              hipStream_t stream)
{
    const float* x        = (const float*)d_in[0];
    const float* pe_w     = (const float*)d_in[1];
    const float* pe_b     = (const float*)d_in[2];
    const float* mix1_w   = (const float*)d_in[3];
    const float* mix1_b   = (const float*)d_in[4];
    const float* mix2_w   = (const float*)d_in[5];
    const float* mix2_b   = (const float*)d_in[6];
    const float* qc_w     = (const float*)d_in[7];
    const float* qc_b     = (const float*)d_in[8];
    const float* codebook = (const float*)d_in[9];
    const float* dpre1_w  = (const float*)d_in[10];
    const float* dpre1_b  = (const float*)d_in[11];
    const float* dpre2_w  = (const float*)d_in[12];
    const float* dpre2_b  = (const float*)d_in[13];
    const float* up_w     = (const float*)d_in[14];
    const float* up_b     = (const float*)d_in[15];

    char* W = (char*)d_ws;
    // byte layout; total 63,209,472 B
    ush*   hAh  = (ush*)(W + 0);              // 4,194,304
    ush*   hAl  = (ush*)(W + 4194304);        // 4,194,304
    ush*   hBh  = (ush*)(W + 8388608);        // 4,194,304
    ush*   hBl  = (ush*)(W + 12582912);       // 4,194,304
    // region X (25,165,824): xp h/l before qc; z + zh after
    ush*   xph  = (ush*)(W + 16777216);       // 12,582,912
    ush*   xpl  = (ush*)(W + 29360128);       // 12,582,912
    float* z    = (float*)(W + 16777216);     // 16,777,216
    ush*   zh   = (ush*)(W + 33554432);       //  8,388,608
    ush*   cbh  = (ush*)(W + 41943040);       //  8,388,608
    ush*   cbl  = (ush*)(W + 50331648);       //  8,388,608
    ush*   peh  = (ush*)(W + 58720256);       //    393,216
    ush*   pel  = (ush*)(W + 59113472);       //    393,216
    ush*   m1h  = (ush*)(W + 59506688);       //    131,072
    ush*   m1l  = (ush*)(W + 59637760);
    ush*   m2h  = (ush*)(W + 59768832);
    ush*   m2l  = (ush*)(W + 59899904);
    ush*   qch  = (ush*)(W + 60030976);       //    262,144
    ush*   qcl  = (ush*)(W + 60293120);
    ush*   d1h  = (ush*)(W + 60555264);       //    262,144
    ush*   d1l  = (ush*)(W + 60817408);
    ush*   d2h  = (ush*)(W + 61079552);       //    131,072
    ush*   d2l  = (ush*)(W + 61210624);
    ush*   uTh  = (ush*)(W + 61341696);       //    393,216
    ush*   uTl  = (ush*)(W + 61734912);
    float* cnorm= (float*)(W + 62128128);     //     32,768
    int*   cand = (int*)(W + 62160896);       //  1,048,576  (ends 63,209,472)

    float* dec     = (float*)d_out;
    float* diffp   = dec + 6291456;
    float* idx_out = (float*)d_out + 6291457;

    // ---- prep: split everything to bf16 h/l once ----
    split_hl<<<96,   256, 0, stream>>>(pe_w,    peh, pel);
    split_hl<<<32,   256, 0, stream>>>(mix1_w,  m1h, m1l);
    split_hl<<<32,   256, 0, stream>>>(mix2_w,  m2h, m2l);
    split_hl<<<64,   256, 0, stream>>>(qc_w,    qch, qcl);
    split_hl<<<64,   256, 0, stream>>>(dpre1_w, d1h, d1l);
    split_hl<<<32,   256, 0, stream>>>(dpre2_w, d2h, d2l);
    split_hl<<<2048, 256, 0, stream>>>(codebook, cbh, cbl);
    split_x<<<3072,  256, 0, stream>>>(x, xph, xpl);
    transpose_upw_split<<<768, 256, 0, stream>>>(up_w, uTh, uTl);
    cb_norm<<<2048, 256, 0, stream>>>(codebook, cnorm);

    // ---- encoder (4-pass == f32-exact to 2^-18) ----
    gemm_bf2<4, 0, 0, true ><<<dim3(64, 4),  256, 0, stream>>>(xph, xpl, peh, pel, pe_b,   nullptr, hAh, hAl, nullptr, 256, 768, 12);
    gemm_bf2<4, 0, 0, true ><<<dim3(64, 4),  256, 0, stream>>>(hAh, hAl, m1h, m1l, mix1_b, nullptr, hBh, hBl, nullptr, 256, 256, 4);
    gemm_bf2<4, 0, 0, false><<<dim3(64, 4),  256, 0, stream>>>(hBh, hBl, m2h, m2l, mix2_b, nullptr, hAh, hAl, nullptr, 256, 256, 4);
    gemm_bf2<4, 0, 1, false><<<dim3(64, 8),  256, 0, stream>>>(hAh, hAl, qch, qcl, qc_b,   z,       zh,  nullptr, nullptr, 512, 256, 4);

    // ---- VQ: approx scan -> exact rescore ----
    vq_scan<<<dim3(64, 8), 256, 0, stream>>>(zh, cbh, cnorm, cand);
    hipMemsetAsync(diffp, 0, sizeof(float), stream);
    exact_select<<<TOK / 4, 256, 0, stream>>>(z, codebook, cand, 32, idx_out, diffp);

    // ---- decoder (3-pass) ----
    gemm_bf2<3, 2, 0, true ><<<dim3(64, 4),  256, 0, stream>>>(cbh, cbl, d1h, d1l, dpre1_b, nullptr, hAh, hAl, idx_out, 256, 512, 8);
    gemm_bf2<3, 0, 0, true ><<<dim3(64, 4),  256, 0, stream>>>(hAh, hAl, d2h, d2l, dpre2_b, nullptr, hBh, hBl, nullptr, 256, 256, 4);
    gemm_bf2<3, 0, 2, false><<<dim3(64, 12), 256, 0, stream>>>(hBh, hBl, uTh, uTl, up_b,    dec,     nullptr, nullptr, nullptr, 768, 256, 4);
}

// Round 11
// 719.946 us; speedup vs baseline: 1.0031x; 1.0031x over previous
//
#include <hip/hip_runtime.h>
#include <hip/hip_bf16.h>
#include <float.h>

// ---------------------------------------------------------------------------
// NonOverlappingFlatVQVAE forward, MI355X (gfx950).
// Round 11: R10 pipeline + XCD-locality remap (T1).
// Diagnosis R6/R7/R10: staging is latency-bound at ~3 TB/s (4.8 B/cyc/CU);
// default block->XCD round-robin makes cb stages L3-latency. Fix: 1D grid,
// cy = bid & 7 so XCD k exclusively serves code-slice k (cb slice + z tile
// become L2-resident); bijective chunked decode for GEMMs.
//   encoder GEMMs : bf16x2, 4 passes  [R7/R10-verified numerics]
//   decoder GEMMs : bf16x2, 3 passes  [R7/R10-verified numerics]
//   VQ stage 1    : bf16-hi scan, top-2 per 16 slots -> 32 cand/token
//   VQ stage 2    : exact f64 rescore -> true argmin + diff [R6-verified]
// ws budget 63,209,472 B (>= proven available). idx written as float.
// ---------------------------------------------------------------------------

#define TOK   8192
#define CBK   8192
#define CBD   512

typedef short  short8v __attribute__((ext_vector_type(8)));
typedef float  f32x4   __attribute__((ext_vector_type(4)));
typedef unsigned short ush;

__device__ __forceinline__ unsigned short f2bf(float x) {
    union { __hip_bfloat16 b; unsigned short u; } c;
    c.b = __float2bfloat16(x);
    return c.u;
}
__device__ __forceinline__ float bf2f(unsigned short h) {
    return __uint_as_float((unsigned)h << 16);
}

// direct global->LDS 16B copy; LDS dest is wave-uniform base + lane*16 (HW).
__device__ __forceinline__ void gload16(const void* g, void* l) {
    __builtin_amdgcn_global_load_lds(
        (const __attribute__((address_space(1))) unsigned int*)g,
        (__attribute__((address_space(3))) unsigned int*)l, 16, 0, 0);
}

// ======================= pipelined bf16x2 MFMA GEMM ========================
// C[M,N] = A[M,K] x Bw[N,K]^T + bias. Tile 128x64, K-step 64, 4 waves (2x2).
// 1D grid 64*ny; bijective chunked XCD decode: xcd = bid&7, lid = xcd*q + bid/8,
// xb = lid/ny (A-panel sharers -> same XCD L2), yb = lid%ny.
// Staging: global_load_lds w16, source pre-swizzled chunk c = p ^ (r&7),
// linear LDS dest, read with same XOR (R6/R10: SQ_LDS_BANK_CONFLICT = 0).
// AMODE: 0 dense, 2 row-gather via float idx. STMODE: 0 ->(Ch,Cl) bf16 pair,
// 1 -> Cf f32 + Ch bf16, 2 -> f32 scatter to dec[B,3,256,256] (bias[n>>8]).
template<int NPASS, int AMODE, int STMODE, bool RELU>
__global__ __launch_bounds__(256)
void gemm_bf2(const ush* __restrict__ Ah, const ush* __restrict__ Al,
              const ush* __restrict__ Bh, const ush* __restrict__ Bl,
              const float* __restrict__ bias,
              float* __restrict__ Cf, ush* __restrict__ Ch, ush* __restrict__ Cl,
              const float* __restrict__ rowidx, int N, int K, int NT)
{
    __shared__ __align__(16) ush AzH[2][128 * 64];
    __shared__ __align__(16) ush AzL[2][128 * 64];
    __shared__ __align__(16) ush BcH[2][64 * 64];
    __shared__ __align__(16) ush BcL[2][64 * 64];

    const int tid = threadIdx.x, lane = tid & 63, wid = tid >> 6;
    const int wr = wid >> 1, wc = wid & 1;
    // XCD-bijective decode (nwg = 64*ny, always % 8 == 0)
    const int nwg = gridDim.x;
    const int ny  = nwg >> 6;
    const int q   = nwg >> 3;
    const int lid = (blockIdx.x & 7) * q + (blockIdx.x >> 3);
    const int m0  = (lid / ny) * 128, n0 = (lid % ny) * 64;
    const int l15 = lane & 15, l4 = lane >> 4;

    // per-lane staging source offsets (elements); per-wave LDS chunk bases
    size_t aoff[4];
    int    aldst[4];
    #pragma unroll
    for (int i = 0; i < 4; ++i) {
        const int ci = (wid * 4 + i) * 64 + lane;
        const int r = ci >> 3, p = ci & 7;
        size_t rowbase;
        if constexpr (AMODE == 2) rowbase = (size_t)((int)rowidx[m0 + r]) * K;
        else                      rowbase = (size_t)(m0 + r) * K;
        aoff[i]  = rowbase + ((p ^ (r & 7)) << 3);
        aldst[i] = (wid * 4 + i) * 512;
    }
    size_t boff[2];
    int    bldst[2];
    #pragma unroll
    for (int i = 0; i < 2; ++i) {
        const int ci = (wid * 2 + i) * 64 + lane;
        const int r = ci >> 3, p = ci & 7;
        boff[i]  = (size_t)(n0 + r) * K + ((p ^ (r & 7)) << 3);
        bldst[i] = (wid * 2 + i) * 512;
    }

    auto STAGE = [&](int t, int b) {
        const int k0 = t << 6;
        #pragma unroll
        for (int i = 0; i < 4; ++i) {
            gload16(Ah + aoff[i] + k0, &AzH[b][aldst[i]]);
            gload16(Al + aoff[i] + k0, &AzL[b][aldst[i]]);
        }
        #pragma unroll
        for (int i = 0; i < 2; ++i) {
            gload16(Bh + boff[i] + k0, &BcH[b][bldst[i]]);
            gload16(Bl + boff[i] + k0, &BcL[b][bldst[i]]);
        }
    };

    f32x4 acc[4][2];
    #pragma unroll
    for (int mi = 0; mi < 4; ++mi)
        #pragma unroll
        for (int nj = 0; nj < 2; ++nj)
            acc[mi][nj] = (f32x4){0.f, 0.f, 0.f, 0.f};

    STAGE(0, 0);
    __syncthreads();
    for (int t = 0; t < NT; ++t) {
        const int b = t & 1;
        if (t + 1 < NT) STAGE(t + 1, b ^ 1);
        #pragma unroll
        for (int ks = 0; ks < 2; ++ks) {
            short8v aFh[4], aFl[4];
            #pragma unroll
            for (int mi = 0; mi < 4; ++mi) {
                const int r = wr * 64 + mi * 16 + l15;
                const int off = r * 64 + (((ks * 4 + l4) ^ (r & 7)) << 3);
                aFh[mi] = *(const short8v*)(&AzH[b][off]);
                aFl[mi] = *(const short8v*)(&AzL[b][off]);
            }
            #pragma unroll
            for (int nj = 0; nj < 2; ++nj) {
                const int rn = wc * 32 + nj * 16 + l15;
                const int off = rn * 64 + (((ks * 4 + l4) ^ (rn & 7)) << 3);
                const short8v bh = *(const short8v*)(&BcH[b][off]);
                const short8v bl = *(const short8v*)(&BcL[b][off]);
                #pragma unroll
                for (int mi = 0; mi < 4; ++mi) {
                    acc[mi][nj] = __builtin_amdgcn_mfma_f32_16x16x32_bf16(aFh[mi], bh, acc[mi][nj], 0, 0, 0);
                    acc[mi][nj] = __builtin_amdgcn_mfma_f32_16x16x32_bf16(aFh[mi], bl, acc[mi][nj], 0, 0, 0);
                    acc[mi][nj] = __builtin_amdgcn_mfma_f32_16x16x32_bf16(aFl[mi], bh, acc[mi][nj], 0, 0, 0);
                    if constexpr (NPASS == 4)
                        acc[mi][nj] = __builtin_amdgcn_mfma_f32_16x16x32_bf16(aFl[mi], bl, acc[mi][nj], 0, 0, 0);
                }
            }
        }
        __syncthreads();
    }

    // epilogue: C/D layout col=lane&15 (n), row=(lane>>4)*4+i (m) [R6-verified]
    #pragma unroll
    for (int nj = 0; nj < 2; ++nj) {
        const int n = n0 + wc * 32 + nj * 16 + l15;
        const float bv = (STMODE == 2) ? bias[n >> 8] : bias[n];
        #pragma unroll
        for (int mi = 0; mi < 4; ++mi) {
            #pragma unroll
            for (int i = 0; i < 4; ++i) {
                const int m = m0 + wr * 64 + mi * 16 + l4 * 4 + i;
                float v = acc[mi][nj][i] + bv;
                if constexpr (RELU) v = fmaxf(v, 0.f);
                if constexpr (STMODE == 0) {
                    const unsigned short h = f2bf(v);
                    Ch[(size_t)m * N + n] = h;
                    Cl[(size_t)m * N + n] = f2bf(v - bf2f(h));
                } else if constexpr (STMODE == 1) {
                    Cf[(size_t)m * N + n] = v;
                    Ch[(size_t)m * N + n] = f2bf(v);
                } else {
                    const int o = n >> 8, p = (n >> 4) & 15, qq = n & 15;
                    const int b2 = m >> 8, ii = (m >> 4) & 15, jj = m & 15;
                    Cf[((size_t)(b2 * 3 + o) * 256 + ii * 16 + p) * 256 + jj * 16 + qq] = v;
                }
            }
        }
    }
}

// ================== pipelined VQ stage 1 (bf16-hi scan) ====================
// 1D grid 512; cy = bid & 7 -> XCD k exclusively serves code-slice k:
// its 1MB cb-hi slice is L2-resident, z-tile re-stages hit L2.
// Block 4 waves (2x2), tile 128 tok x 128 codes, K-step 64, LDS 64KB dbuf.
__global__ __launch_bounds__(256)
void vq_scan(const ush* __restrict__ zh, const ush* __restrict__ cbh,
             const float* __restrict__ cnorm, int* __restrict__ cand)
{
    __shared__ __align__(16) ush Az[2][128 * 64];
    __shared__ __align__(16) ush Bc[2][128 * 64];

    const int tid = threadIdx.x, lane = tid & 63, wid = tid >> 6;
    const int wr = wid >> 1, wc = wid & 1;
    const int cy = blockIdx.x & 7;           // XCD-local code slice
    const int m0 = (blockIdx.x >> 3) * 128;  // token tile
    const int l15 = lane & 15, l4 = lane >> 4;

    size_t soff[4];
    int    ldst[4];
    #pragma unroll
    for (int i = 0; i < 4; ++i) {
        const int ci = (wid * 4 + i) * 64 + lane;
        const int r = ci >> 3, p = ci & 7;
        soff[i] = (size_t)r * CBD + ((p ^ (r & 7)) << 3);
        ldst[i] = (wid * 4 + i) * 512;
    }

    auto STAGE = [&](int t, int b) {
        const int chk = t >> 3, k0 = (t & 7) << 6;
        const size_t ab = (size_t)m0 * CBD + k0;
        const size_t bb = (size_t)(cy * 1024 + chk * 128) * CBD + k0;
        #pragma unroll
        for (int i = 0; i < 4; ++i) {
            gload16(zh  + ab + soff[i], &Az[b][ldst[i]]);
            gload16(cbh + bb + soff[i], &Bc[b][ldst[i]]);
        }
    };

    float r1[16], r2[16];
    int   i1[16], i2[16];
    #pragma unroll
    for (int r = 0; r < 16; ++r) { r1[r] = FLT_MAX; r2[r] = FLT_MAX; i1[r] = 0; i2[r] = 0; }

    f32x4 acc[4][4];
    STAGE(0, 0);
    __syncthreads();
    for (int t = 0; t < 64; ++t) {
        const int b = t & 1;
        if (t < 63) STAGE(t + 1, b ^ 1);
        if ((t & 7) == 0) {
            #pragma unroll
            for (int mi = 0; mi < 4; ++mi)
                #pragma unroll
                for (int nj = 0; nj < 4; ++nj)
                    acc[mi][nj] = (f32x4){0.f, 0.f, 0.f, 0.f};
        }
        #pragma unroll
        for (int ks = 0; ks < 2; ++ks) {
            short8v aF[4];
            #pragma unroll
            for (int mi = 0; mi < 4; ++mi) {
                const int r = wr * 64 + mi * 16 + l15;
                aF[mi] = *(const short8v*)(&Az[b][r * 64 + (((ks * 4 + l4) ^ (r & 7)) << 3)]);
            }
            #pragma unroll
            for (int nj = 0; nj < 4; ++nj) {
                const int rn = wc * 64 + nj * 16 + l15;
                const short8v bF = *(const short8v*)(&Bc[b][rn * 64 + (((ks * 4 + l4) ^ (rn & 7)) << 3)]);
                #pragma unroll
                for (int mi = 0; mi < 4; ++mi)
                    acc[mi][nj] = __builtin_amdgcn_mfma_f32_16x16x32_bf16(aF[mi], bF, acc[mi][nj], 0, 0, 0);
            }
        }
        if ((t & 7) == 7) {
            const int c0 = cy * 1024 + (t >> 3) * 128;
            #pragma unroll
            for (int nj = 0; nj < 4; ++nj) {
                const int code = c0 + wc * 64 + nj * 16 + l15;
                const float cn = cnorm[code];
                #pragma unroll
                for (int mi = 0; mi < 4; ++mi) {
                    #pragma unroll
                    for (int i = 0; i < 4; ++i) {
                        const float d = cn - 2.0f * acc[mi][nj][i];
                        const int rr = mi * 4 + i;
                        if (d < r1[rr]) { r2[rr] = r1[rr]; i2[rr] = i1[rr]; r1[rr] = d; i1[rr] = code; }
                        else if (d < r2[rr]) { r2[rr] = d; i2[rr] = code; }
                    }
                }
            }
        }
        __syncthreads();
    }

    // merge top-2 across the 16 l15 lanes sharing each token row
    #pragma unroll
    for (int r = 0; r < 16; ++r) {
        float a1 = r1[r], a2 = r2[r];
        int   x1 = i1[r], x2 = i2[r];
        #pragma unroll
        for (int off = 1; off < 16; off <<= 1) {
            const float b1 = __shfl_xor(a1, off), b2 = __shfl_xor(a2, off);
            const int   y1 = __shfl_xor(x1, off), y2 = __shfl_xor(x2, off);
            if (b1 < a1) {
                const float n2 = (a1 < b2) ? a1 : b2;
                const int   m2 = (a1 < b2) ? x1 : y2;
                a2 = n2; x2 = m2; a1 = b1; x1 = y1;
            } else {
                if (b1 < a2) { a2 = b1; x2 = y1; }
            }
        }
        r1[r] = a1; i1[r] = x1; r2[r] = a2; i2[r] = x2;
    }
    if (l15 == 0) {
        const int slot = cy * 2 + wc;
        #pragma unroll
        for (int mi = 0; mi < 4; ++mi)
            #pragma unroll
            for (int i = 0; i < 4; ++i) {
                const int tok = m0 + wr * 64 + mi * 16 + l4 * 4 + i;
                cand[(slot * 2 + 0) * TOK + tok] = i1[mi * 4 + i];
                cand[(slot * 2 + 1) * TOK + tok] = i2[mi * 4 + i];
            }
    }
}

// ============ stage 2: exact f64 rescore of candidates + diff ==============
__global__ __launch_bounds__(256)
void exact_select(const float* __restrict__ z, const float* __restrict__ cb,
                  const int* __restrict__ cand, int ncand,
                  float* __restrict__ idx_out, float* __restrict__ diffp)
{
    const int t    = blockIdx.x * 4 + (threadIdx.x >> 6);
    const int lane = threadIdx.x & 63;

    const float4 za = *(const float4*)(z + (size_t)t * CBD + lane * 8);
    const float4 zb = *(const float4*)(z + (size_t)t * CBD + lane * 8 + 4);
    const double zd[8] = {za.x, za.y, za.z, za.w, zb.x, zb.y, zb.z, zb.w};

    double bestd = DBL_MAX;
    int    besti = 0x7fffffff;
    for (int c = 0; c < ncand; ++c) {
        const int code = cand[c * TOK + t];
        const float4 ca  = *(const float4*)(cb + (size_t)code * CBD + lane * 8);
        const float4 cbv = *(const float4*)(cb + (size_t)code * CBD + lane * 8 + 4);
        const double cd[8] = {ca.x, ca.y, ca.z, ca.w, cbv.x, cbv.y, cbv.z, cbv.w};
        double s = 0.0;
        #pragma unroll
        for (int j = 0; j < 8; ++j) { const double d = cd[j] - zd[j]; s = fma(d, d, s); }
        #pragma unroll
        for (int off = 32; off >= 1; off >>= 1) s += __shfl_down(s, off);
        s = __shfl(s, 0);
        if (s < bestd || (s == bestd && code < besti)) { bestd = s; besti = code; }
    }
    if (lane == 0) {
        idx_out[t] = (float)besti;
        atomicAdd(diffp, (float)(bestd * (1.0 / ((double)TOK * CBD))));
    }
}

// ============================ prep kernels =================================
__global__ __launch_bounds__(256)
void cb_norm(const float* __restrict__ cb, float* __restrict__ cnorm)
{
    const int row  = blockIdx.x * 4 + (threadIdx.x >> 6);
    const int lane = threadIdx.x & 63;
    const float4* p = (const float4*)(cb + (size_t)row * CBD + lane * 8);
    const float4 a = p[0], b = p[1];
    double s = (double)a.x*a.x + (double)a.y*a.y + (double)a.z*a.z + (double)a.w*a.w
             + (double)b.x*b.x + (double)b.y*b.y + (double)b.z*b.z + (double)b.w*b.w;
    #pragma unroll
    for (int off = 32; off >= 1; off >>= 1) s += __shfl_down(s, off);
    if (lane == 0) cnorm[row] = (float)s;
}

__device__ __forceinline__ void split8(const float* __restrict__ src, size_t i8,
                                       ush* __restrict__ h, ush* __restrict__ l)
{
    const float4 a = *(const float4*)(src + i8 * 8);
    const float4 b = *(const float4*)(src + i8 * 8 + 4);
    const float xs[8] = {a.x, a.y, a.z, a.w, b.x, b.y, b.z, b.w};
    union { unsigned short u[8]; short8v v; } H, L;
    #pragma unroll
    for (int j = 0; j < 8; ++j) {
        const unsigned short hh = f2bf(xs[j]);
        H.u[j] = hh;
        L.u[j] = f2bf(xs[j] - bf2f(hh));
    }
    *(short8v*)(h + i8 * 8) = H.v;
    *(short8v*)(l + i8 * 8) = L.v;
}

// f32 -> (h,l) split (codebook; n % 2048 == 0)
__global__ __launch_bounds__(256)
void split_hl(const float* __restrict__ src, ush* __restrict__ h, ush* __restrict__ l)
{
    split8(src, (size_t)blockIdx.x * 256 + threadIdx.x, h, l);
}

// all 6 weight matrices split in one launch (320 blocks)
__global__ __launch_bounds__(256)
void split_weights(const float* __restrict__ pe_w,  const float* __restrict__ m1w,
                   const float* __restrict__ m2w,   const float* __restrict__ qcw,
                   const float* __restrict__ d1w,   const float* __restrict__ d2w,
                   ush* peh, ush* pel, ush* m1h, ush* m1l, ush* m2h, ush* m2l,
                   ush* qch, ush* qcl, ush* d1h, ush* d1l, ush* d2h, ush* d2l)
{
    const int b = blockIdx.x;
    const float* src; ush *h, *l; int base;
    if      (b < 96)  { src = pe_w; h = peh; l = pel; base = b; }
    else if (b < 128) { src = m1w;  h = m1h; l = m1l; base = b - 96; }
    else if (b < 160) { src = m2w;  h = m2h; l = m2l; base = b - 128; }
    else if (b < 224) { src = qcw;  h = qch; l = qcl; base = b - 160; }
    else if (b < 288) { src = d1w;  h = d1h; l = d1l; base = b - 224; }
    else              { src = d2w;  h = d2h; l = d2l; base = b - 288; }
    split8(src, (size_t)base * 256 + threadIdx.x, h, l);
}

// patchify gather + split: x[32,3,256,256] -> xph/xpl [8192][768]
__global__ __launch_bounds__(256)
void split_x(const float* __restrict__ x, ush* __restrict__ xh, ush* __restrict__ xl)
{
    const int i8 = blockIdx.x * 256 + threadIdx.x;   // < 786432
    const int m = i8 / 96, kc = (i8 % 96) * 8;
    const int b = m >> 8, ii = (m >> 4) & 15, jj = m & 15;
    const int c = kc >> 8, p = (kc >> 4) & 15, q = kc & 15;
    const float* src = x + ((size_t)(b * 3 + c) * 256 + ii * 16 + p) * 256 + jj * 16 + q;
    const float4 a = *(const float4*)src;
    const float4 d = *(const float4*)(src + 4);
    const float xs[8] = {a.x, a.y, a.z, a.w, d.x, d.y, d.z, d.w};
    union { unsigned short u[8]; short8v v; } H, L;
    #pragma unroll
    for (int j = 0; j < 8; ++j) {
        const unsigned short hh = f2bf(xs[j]);
        H.u[j] = hh;
        L.u[j] = f2bf(xs[j] - bf2f(hh));
    }
    *(short8v*)(xh + (size_t)i8 * 8) = H.v;
    *(short8v*)(xl + (size_t)i8 * 8) = L.v;
}

// up_w [256,768] -> upT h/l [768][256]
__global__ __launch_bounds__(256)
void transpose_upw_split(const float* __restrict__ up_w, ush* __restrict__ th, ush* __restrict__ tl)
{
    const int id = blockIdx.x * 256 + threadIdx.x;   // < 196608
    const int n = id >> 8, c = id & 255;
    const float v = up_w[c * 768 + n];
    const unsigned short h = f2bf(v);
    th[id] = h;
    tl[id] = f2bf(v - bf2f(h));
}

// ---------------------------------------------------------------------------
extern "C" void kernel_launch(void* const* d_in, const int* in_sizes, int n_in,
                              void* d_out, int out_size, void* d_ws, size_t ws_size,
                              hipStream_t stream)
{
    const float* x        = (const float*)d_in[0];
    const float* pe_w     = (const float*)d_in[1];
    const float* pe_b     = (const float*)d_in[2];
    const float* mix1_w   = (const float*)d_in[3];
    const float* mix1_b   = (const float*)d_in[4];
    const float* mix2_w   = (const float*)d_in[5];
    const float* mix2_b   = (const float*)d_in[6];
    const float* qc_w     = (const float*)d_in[7];
    const float* qc_b     = (const float*)d_in[8];
    const float* codebook = (const float*)d_in[9];
    const float* dpre1_w  = (const float*)d_in[10];
    const float* dpre1_b  = (const float*)d_in[11];
    const float* dpre2_w  = (const float*)d_in[12];
    const float* dpre2_b  = (const float*)d_in[13];
    const float* up_w     = (const float*)d_in[14];
    const float* up_b     = (const float*)d_in[15];

    char* W = (char*)d_ws;
    // byte layout; total 63,209,472 B
    ush*   hAh  = (ush*)(W + 0);              // 4,194,304
    ush*   hAl  = (ush*)(W + 4194304);        // 4,194,304
    ush*   hBh  = (ush*)(W + 8388608);        // 4,194,304
    ush*   hBl  = (ush*)(W + 12582912);       // 4,194,304
    // region X (25,165,824): xp h/l before qc; z + zh after
    ush*   xph  = (ush*)(W + 16777216);       // 12,582,912
    ush*   xpl  = (ush*)(W + 29360128);       // 12,582,912
    float* z    = (float*)(W + 16777216);     // 16,777,216
    ush*   zh   = (ush*)(W + 33554432);       //  8,388,608
    ush*   cbh  = (ush*)(W + 41943040);       //  8,388,608
    ush*   cbl  = (ush*)(W + 50331648);       //  8,388,608
    ush*   peh  = (ush*)(W + 58720256);       //    393,216
    ush*   pel  = (ush*)(W + 59113472);       //    393,216
    ush*   m1h  = (ush*)(W + 59506688);       //    131,072
    ush*   m1l  = (ush*)(W + 59637760);
    ush*   m2h  = (ush*)(W + 59768832);
    ush*   m2l  = (ush*)(W + 59899904);
    ush*   qch  = (ush*)(W + 60030976);       //    262,144
    ush*   qcl  = (ush*)(W + 60293120);
    ush*   d1h  = (ush*)(W + 60555264);       //    262,144
    ush*   d1l  = (ush*)(W + 60817408);
    ush*   d2h  = (ush*)(W + 61079552);       //    131,072
    ush*   d2l  = (ush*)(W + 61210624);
    ush*   uTh  = (ush*)(W + 61341696);       //    393,216
    ush*   uTl  = (ush*)(W + 61734912);
    float* cnorm= (float*)(W + 62128128);     //     32,768
    int*   cand = (int*)(W + 62160896);       //  1,048,576  (ends 63,209,472)

    float* dec     = (float*)d_out;
    float* diffp   = dec + 6291456;
    float* idx_out = (float*)d_out + 6291457;

    // ---- prep: split everything to bf16 h/l once ----
    split_weights<<<320, 256, 0, stream>>>(pe_w, mix1_w, mix2_w, qc_w, dpre1_w, dpre2_w,
                                           peh, pel, m1h, m1l, m2h, m2l,
                                           qch, qcl, d1h, d1l, d2h, d2l);
    split_hl<<<2048, 256, 0, stream>>>(codebook, cbh, cbl);
    split_x<<<3072,  256, 0, stream>>>(x, xph, xpl);
    transpose_upw_split<<<768, 256, 0, stream>>>(up_w, uTh, uTl);
    cb_norm<<<2048, 256, 0, stream>>>(codebook, cnorm);

    // ---- encoder (4-pass == f32-exact to 2^-18); 1D grids, XCD decode ----
    gemm_bf2<4, 0, 0, true ><<<256, 256, 0, stream>>>(xph, xpl, peh, pel, pe_b,   nullptr, hAh, hAl, nullptr, 256, 768, 12);
    gemm_bf2<4, 0, 0, true ><<<256, 256, 0, stream>>>(hAh, hAl, m1h, m1l, mix1_b, nullptr, hBh, hBl, nullptr, 256, 256, 4);
    gemm_bf2<4, 0, 0, false><<<256, 256, 0, stream>>>(hBh, hBl, m2h, m2l, mix2_b, nullptr, hAh, hAl, nullptr, 256, 256, 4);
    gemm_bf2<4, 0, 1, false><<<512, 256, 0, stream>>>(hAh, hAl, qch, qcl, qc_b,   z,       zh,  nullptr, nullptr, 512, 256, 4);

    // ---- VQ: approx scan (XCD-localized) -> exact rescore ----
    vq_scan<<<512, 256, 0, stream>>>(zh, cbh, cnorm, cand);
    hipMemsetAsync(diffp, 0, sizeof(float), stream);
    exact_select<<<TOK / 4, 256, 0, stream>>>(z, codebook, cand, 32, idx_out, diffp);

    // ---- decoder (3-pass) ----
    gemm_bf2<3, 2, 0, true ><<<256, 256, 0, stream>>>(cbh, cbl, d1h, d1l, dpre1_b, nullptr, hAh, hAl, idx_out, 256, 512, 8);
    gemm_bf2<3, 0, 0, true ><<<256, 256, 0, stream>>>(hAh, hAl, d2h, d2l, dpre2_b, nullptr, hBh, hBl, nullptr, 256, 256, 4);
    gemm_bf2<3, 0, 2, false><<<768, 256, 0, stream>>>(hBh, hBl, uTh, uTl, up_b,    dec,     nullptr, nullptr, nullptr, 768, 256, 4);
}